// Round 5
// baseline (240.549 us; speedup 1.0000x reference)
//
#include <hip/hip_runtime.h>
#include <math.h>

#define EPS 1e-5f
#define T_LEN 8192
#define WAVES_PER_BLOCK 4

// One WAVE = one (b,c) row. No barriers, no LDS, no DS-pipe traffic at all.
// Row = 32 chunks x 64 granules (float4); lane owns granule (c*64+lane).
// Depth-4 register-rotated load pipeline keeps 4 coalesced 1KB loads in
// flight per lane; compiler emits counted vmcnt waits.
// Scan: canonical GCN wave64 DPP scan (rocPRIM pattern) — 6 VALU adds per
// quantity (row_shr 1/2/4/8, row_bcast:15 rows{1,3}, row_bcast:31 rows{2,3})
// instead of 12 ds_permute shfl_up's: ~10x lower dependent latency, VALU pipe
// only. Exclusive prefix = inclusive - own (exact at lane 0, ~ulp elsewhere).
// Per-element 1/count rcp's are data-independent -> hoisted off the replay
// dependency chain. Chunk totals carried via readlane(63) scalar adds.
template<int CTRL, int RM>
__device__ __forceinline__ float dpp_add(float x) {
    int sh = __builtin_amdgcn_update_dpp(0, __float_as_int(x),
                                         CTRL, RM, 0xF, false);
    return x + __int_as_float(sh);
}

__device__ __forceinline__ float wave64_incl_scan(float x) {
    x = dpp_add<0x111, 0xF>(x);   // row_shr:1
    x = dpp_add<0x112, 0xF>(x);   // row_shr:2
    x = dpp_add<0x114, 0xF>(x);   // row_shr:4
    x = dpp_add<0x118, 0xF>(x);   // row_shr:8
    x = dpp_add<0x142, 0xA>(x);   // row_bcast:15 -> rows 1,3
    x = dpp_add<0x143, 0xC>(x);   // row_bcast:31 -> rows 2,3
    return x;
}

__global__ __launch_bounds__(256) void causal_ln_kernel(
    const float* __restrict__ x,
    const float* __restrict__ weight,
    const float* __restrict__ bias,
    float* __restrict__ out,
    int C)
{
    const int t    = threadIdx.x;        // 0..255
    const int lane = t & 63;
    const int wid  = t >> 6;             // wave 0..3
    const int row  = blockIdx.x * WAVES_PER_BLOCK + wid;

    const float wv = weight[row % C];
    const float bv = bias[row % C];

    const float4* xg = (const float4*)(x   + (long long)row * T_LEN);
    float4*       og = (float4*)(out + (long long)row * T_LEN);

    // prologue: chunks 0..3 in flight
    float4 buf[4];
#pragma unroll
    for (int j = 0; j < 4; ++j)
        buf[j] = xg[j * 64 + lane];

    float off1 = 0.f, off2 = 0.f;        // totals of all chunks < c

#pragma unroll
    for (int c = 0; c < 32; ++c) {
        float4 cur = buf[c & 3];
        if (c + 4 < 32)
            buf[c & 3] = xg[(c + 4) * 64 + lane];   // refill freed slot

        // 1/count values are data-independent: off the dependent chain
        float cb = (float)((c * 64 + lane) * 4);
        float rcv[4];
#pragma unroll
        for (int i = 0; i < 4; ++i)
            rcv[i] = __builtin_amdgcn_rcpf(cb + (float)(i + 1));

        // lane-local granule sums
        float s  = cur.x + cur.y + cur.z + cur.w;
        float s2 = cur.x * cur.x + cur.y * cur.y
                 + cur.z * cur.z + cur.w * cur.w;

        // wave64 inclusive scan via DPP (two chains interleave in the pipe)
        float ws  = wave64_incl_scan(s);
        float ws2 = wave64_incl_scan(s2);

        // exclusive prefix + running offset from previous chunks
        float run  = off1 + (ws  - s);
        float run2 = off2 + (ws2 - s2);

        // causal replay of the 4 owned elements
        float xs[4] = {cur.x, cur.y, cur.z, cur.w};
#pragma unroll
        for (int i = 0; i < 4; ++i) {
            float xi = xs[i];
            run  += xi;
            run2 += xi * xi;
            float mean = run * rcv[i];
            float var  = fmaxf(run2 * rcv[i] - mean * mean, 0.f);
            float rinv = __builtin_amdgcn_rsqf(var + EPS);
            xs[i] = (xi - mean) * rinv * wv + bv;
        }
        og[c * 64 + lane] = make_float4(xs[0], xs[1], xs[2], xs[3]);

        // carry chunk totals (uniform via readlane -> scalar adds)
        off1 += __int_as_float(__builtin_amdgcn_readlane(__float_as_int(ws),  63));
        off2 += __int_as_float(__builtin_amdgcn_readlane(__float_as_int(ws2), 63));
    }
}

extern "C" void kernel_launch(void* const* d_in, const int* in_sizes, int n_in,
                              void* d_out, int out_size, void* d_ws, size_t ws_size,
                              hipStream_t stream) {
    const float* x      = (const float*)d_in[0];
    const float* weight = (const float*)d_in[1];
    const float* bias   = (const float*)d_in[2];
    float* out          = (float*)d_out;

    const int C = in_sizes[1];            // 512 (weight is [1,C,1])
    const int T = 8192;                   // time length per row
    const int rows = in_sizes[0] / T;     // B*C = 4096

    dim3 grid(rows / WAVES_PER_BLOCK), block(64 * WAVES_PER_BLOCK);
    hipLaunchKernelGGL(causal_ln_kernel, grid, block, 0, stream,
                       x, weight, bias, out, C);
}

// Round 6
// 233.605 us; speedup vs baseline: 1.0297x; 1.0297x over previous
//
#include <hip/hip_runtime.h>
#include <math.h>

#define EPS 1e-5f
#define T_LEN 8192

// One BLOCK (1024 threads, 16 waves) = one (b,c) row; entire 32 KB row is
// loaded in ONE shot (2 float4 loads/thread, 64 KB of reads in flight per
// block) -- memory-level parallelism is structural, not left to the
// scheduler. Thread t owns 8 contiguous elements [8t, 8t+8).
// Scan: 8-elem local sums -> one wave64 DPP scan of (s,s2) (6 VALU adds
// each, no DS pipe) -> exclusive = inclusive - own -> per-wave totals via
// LDS (16 float2, broadcast reads), ONE barrier -> 8-elem causal replay in
// registers -> 2 coalesced float4 stores.
// 1/count table is data-independent: computed under the load shadow.
template<int CTRL, int RM>
__device__ __forceinline__ float dpp_add(float x) {
    int sh = __builtin_amdgcn_update_dpp(0, __float_as_int(x),
                                         CTRL, RM, 0xF, false);
    return x + __int_as_float(sh);
}

__device__ __forceinline__ float wave64_incl_scan(float x) {
    x = dpp_add<0x111, 0xF>(x);   // row_shr:1
    x = dpp_add<0x112, 0xF>(x);   // row_shr:2
    x = dpp_add<0x114, 0xF>(x);   // row_shr:4
    x = dpp_add<0x118, 0xF>(x);   // row_shr:8
    x = dpp_add<0x142, 0xA>(x);   // row_bcast:15 -> rows 1,3
    x = dpp_add<0x143, 0xC>(x);   // row_bcast:31 -> rows 2,3
    return x;
}

__global__ __launch_bounds__(1024, 8) void causal_ln_kernel(
    const float* __restrict__ x,
    const float* __restrict__ weight,
    const float* __restrict__ bias,
    float* __restrict__ out,
    int C)
{
    __shared__ float2 wtot[16];          // per-wave (sum, sumsq) totals

    const int t    = threadIdx.x;        // 0..1023
    const int lane = t & 63;
    const int wid  = t >> 6;             // wave 0..15
    const int row  = blockIdx.x;

    // scalar params early (uniform)
    const float wv = weight[row % C];
    const float bv = bias[row % C];

    // ---- issue BOTH row loads immediately: whole row in flight ----
    const float4* xg = (const float4*)(x + (long long)row * T_LEN);
    float4 v0 = xg[2 * t];
    float4 v1 = xg[2 * t + 1];

    // data-independent 1/count table: executes under the load shadow
    float rcv[8];
#pragma unroll
    for (int i = 0; i < 8; ++i)
        rcv[i] = __builtin_amdgcn_rcpf((float)(8 * t + i + 1));

    float xs[8] = {v0.x, v0.y, v0.z, v0.w, v1.x, v1.y, v1.z, v1.w};

    // thread-local (sum, sumsq) of owned 8 elements
    float s = 0.f, s2 = 0.f;
#pragma unroll
    for (int i = 0; i < 8; ++i) { s += xs[i]; s2 += xs[i] * xs[i]; }

    // wave64 inclusive scan over lanes (thread totals)
    float ws  = wave64_incl_scan(s);
    float ws2 = wave64_incl_scan(s2);

    // cross-wave combine: one barrier
    if (lane == 63) wtot[wid] = make_float2(ws, ws2);
    __syncthreads();

    float off1 = 0.f, off2 = 0.f;
#pragma unroll
    for (int w = 0; w < 15; ++w) {
        if (w < wid) { off1 += wtot[w].x; off2 += wtot[w].y; }
    }

    // exclusive prefix for this thread (inclusive - own; exact at lane 0)
    float run  = off1 + (ws  - s);
    float run2 = off2 + (ws2 - s2);

    // ---- causal replay of the 8 owned elements ----
#pragma unroll
    for (int i = 0; i < 8; ++i) {
        float xi = xs[i];
        run  += xi;
        run2 += xi * xi;
        float mean = run * rcv[i];
        float var  = fmaxf(run2 * rcv[i] - mean * mean, 0.f);
        float rinv = __builtin_amdgcn_rsqf(var + EPS);
        xs[i] = (xi - mean) * rinv * wv + bv;
    }

    // ---- coalesced stores ----
    float4* og = (float4*)(out + (long long)row * T_LEN);
    og[2 * t]     = make_float4(xs[0], xs[1], xs[2], xs[3]);
    og[2 * t + 1] = make_float4(xs[4], xs[5], xs[6], xs[7]);
}

extern "C" void kernel_launch(void* const* d_in, const int* in_sizes, int n_in,
                              void* d_out, int out_size, void* d_ws, size_t ws_size,
                              hipStream_t stream) {
    const float* x      = (const float*)d_in[0];
    const float* weight = (const float*)d_in[1];
    const float* bias   = (const float*)d_in[2];
    float* out          = (float*)d_out;

    const int C = in_sizes[1];            // 512 (weight is [1,C,1])
    const int T = 8192;                   // time length per row
    const int rows = in_sizes[0] / T;     // B*C = 4096

    dim3 grid(rows), block(1024);
    hipLaunchKernelGGL(causal_ln_kernel, grid, block, 0, stream,
                       x, weight, bias, out, C);
}